// Round 11
// baseline (726.449 us; speedup 1.0000x reference)
//
#include <hip/hip_runtime.h>
#include <cfloat>

// Farthest Point Sampling: B=32, N=200000, M=128.
// r10 scan (packed-f32, PT=26, 7 pairs VGPR + 6 pairs LDS) + flattened tail:
// per-wave tag publish (128 slots/batch/parity, relaxed u64, XCD-local L2),
// wave0-only poll+reduce, ONE __syncthreads, all-wave winner-coord fetch.
#define B_    32
#define N_    200000
#define M_    128
#define BPB   8                    // blocks per batch
#define T_    1024                 // threads per block
#define PT    26                   // points per thread (13 pairs)
#define NPAIR 13
#define PVP   7                    // pairs in VGPRs (j = 0..13)
#define CHUNK (T_ * PT)            // 26624 points per block; 8*26624 >= N

#define SPIN_CAP (1 << 20)         // safety valve: never hang the container

typedef float v2f __attribute__((ext_vector_type(2)));

__global__ __launch_bounds__(T_, 4)
void fps_kernel(const float* __restrict__ pts, int* __restrict__ out,
                unsigned long long* __restrict__ tags) {
#pragma clang fp contract(off)
  const int tid = threadIdx.x;
  const int bid = blockIdx.x;
  // XCD-local batches: blocks round-robin XCDs by bid&7 (measured m09).
  // All 8 blocks of a batch -> one XCD -> tag exchange stays in that L2.
  const int xcd = bid & 7;
  const int sl8 = bid >> 3;                  // 0..31 within this XCD
  const int b   = ((sl8 >> 3) << 3) | xcd;   // batch (b&7 == xcd)
  const int c   = sl8 & 7;                   // chunk within batch
  const int wave = tid >> 6;
  const int lane = tid & 63;

  const float* __restrict__ P = pts + (size_t)b * (size_t)(N_ * 3);
  const int base = c * CHUNK + tid;          // this thread's j=0 global index

  // 3 arrays x [3][1024] float4 = 144 KiB -> exactly 1 block/CU.
  // sX[g][tid] holds x of points j = 14+4g .. 17+4g (thread-private column).
  __shared__ float4 sX[3][T_], sY[3][T_], sZ[3][T_];
  __shared__ int    sFar;                    // winner index mailbox

  // ---- one-time load ----
  v2f x2[PVP], y2[PVP], z2[PVP], md2[NPAIR];
  #pragma unroll
  for (int p = 0; p < PVP; ++p) {
    const int j0 = 2 * p, j1 = 2 * p + 1;
    const int g0 = base + j0 * T_, g1 = base + j1 * T_;
    float m0, m1;
    if (g0 < N_) {
      const float* q = P + (size_t)g0 * 3;
      x2[p].x = q[0]; y2[p].x = q[1]; z2[p].x = q[2];
      m0 = __builtin_huge_valf();
    } else { x2[p].x = 0.f; y2[p].x = 0.f; z2[p].x = 0.f; m0 = -FLT_MAX; }
    if (g1 < N_) {
      const float* q = P + (size_t)g1 * 3;
      x2[p].y = q[0]; y2[p].y = q[1]; z2[p].y = q[2];
      m1 = __builtin_huge_valf();
    } else { x2[p].y = 0.f; y2[p].y = 0.f; z2[p].y = 0.f; m1 = -FLT_MAX; }
    md2[p].x = m0; md2[p].y = m1;
  }
  #pragma unroll
  for (int g = 0; g < 3; ++g) {
    float qx[4], qy[4], qz[4];
    #pragma unroll
    for (int q = 0; q < 4; ++q) {
      const int j = 14 + 4 * g + q;
      const int gg = base + j * T_;
      float m;
      if (gg < N_) {
        const float* pp = P + (size_t)gg * 3;
        qx[q] = pp[0]; qy[q] = pp[1]; qz[q] = pp[2];
        m = __builtin_huge_valf();
      } else { qx[q] = 0.f; qy[q] = 0.f; qz[q] = 0.f; m = -FLT_MAX; }
      const int pr = 7 + 2 * g + (q >> 1);   // pair index 7..12
      if ((q & 1) == 0) md2[pr].x = m; else md2[pr].y = m;
    }
    sX[g][tid] = make_float4(qx[0], qx[1], qx[2], qx[3]);
    sY[g][tid] = make_float4(qy[0], qy[1], qy[2], qy[3]);
    sZ[g][tid] = make_float4(qz[0], qz[1], qz[2], qz[3]);
  }
  asm volatile("" ::: "memory");             // keep LDS staging real (r8 bug)
  __syncthreads();

  float cx = P[0], cy = P[1], cz = P[2];     // initial center = point 0
  if (c == 0 && tid == 0) out[b * M_ + 0] = 0;

  for (int it = 1; it < M_; ++it) {
    // ---- packed distance + running-min + 2-parity-chain argmax ----
    // No exclusion select: the chosen point's self-distance is exactly 0
    // (coords bit-exact), min(md,0)=0 never beats any positive min-dist, so
    // the argmax sequence matches the reference (proven r5-r10).
    // Packed ops are per-component rn, fp contract(off) forbids pk_fma ->
    // bit-identical to numpy's ((dx*dx + dy*dy) + dz*dz).
    const v2f C_x = {cx, cx}, C_y = {cy, cy}, C_z = {cz, cz};
    float bvE = -FLT_MAX, bvO = -FLT_MAX;    // even-j / odd-j chains
    int   bjE = 0x7FFF,   bjO = 0x7FFF;

    #pragma unroll
    for (int p = 0; p < PVP; ++p) {
      v2f dx = x2[p] - C_x;
      v2f dy = y2[p] - C_y;
      v2f dz = z2[p] - C_z;
      v2f s  = (dx * dx + dy * dy) + dz * dz; // 3 pk_mul + 2 pk_add, no fma
      v2f mm = __builtin_elementwise_min(md2[p], s);  // np.minimum
      md2[p] = mm;
      bool tE = mm.x > bvE;                  // ascending j: strict >
      bvE = tE ? mm.x : bvE;
      bjE = tE ? 2 * p : bjE;
      bool tO = mm.y > bvO;
      bvO = tO ? mm.y : bvO;
      bjO = tO ? 2 * p + 1 : bjO;
    }
    #pragma unroll
    for (int g = 0; g < 3; ++g) {
      float4 qx = sX[g][tid], qy = sY[g][tid], qz = sZ[g][tid];
      #pragma unroll
      for (int h = 0; h < 2; ++h) {          // two pairs per float4 group
        const int p = 7 + 2 * g + h;         // pair index
        v2f X = (h == 0) ? (v2f){qx.x, qx.y} : (v2f){qx.z, qx.w};
        v2f Y = (h == 0) ? (v2f){qy.x, qy.y} : (v2f){qy.z, qy.w};
        v2f Z = (h == 0) ? (v2f){qz.x, qz.y} : (v2f){qz.z, qz.w};
        v2f dx = X - C_x;
        v2f dy = Y - C_y;
        v2f dz = Z - C_z;
        v2f s  = (dx * dx + dy * dy) + dz * dz;
        v2f mm = __builtin_elementwise_min(md2[p], s);
        md2[p] = mm;
        bool tE = mm.x > bvE;
        bvE = tE ? mm.x : bvE;
        bjE = tE ? 2 * p : bjE;
        bool tO = mm.y > bvO;
        bvO = tO ? mm.y : bvO;
        bjO = tO ? 2 * p + 1 : bjO;
      }
    }
    // merge parity chains (tie -> smaller j = smaller global idx)
    bool tk0 = (bvO > bvE) || (bvO == bvE && bjO < bjE);
    float tv = tk0 ? bvO : bvE;
    int   tj = tk0 ? bjO : bjE;
    int   ti = base + tj * T_;               // reconstruct global idx once

    // ---- wave reduction (64 lanes) ----
    #pragma unroll
    for (int o = 32; o > 0; o >>= 1) {
      float ov = __shfl_xor(tv, o);
      int   oi = __shfl_xor(ti, o);
      bool take = (ov > tv) || (ov == tv && oi < ti);
      tv = take ? ov : tv;
      ti = take ? oi : ti;
    }

    // ---- per-wave publish: candidate goes straight to XCD-local L2 ----
    // 128 slots per (batch, parity): slot = c*16 + wave. One u64 carries
    // (valbits<<32)|(idx<<7)|iter -> RELAXED suffices, no buffer_inv.
    unsigned long long* grp = tags + (((size_t)(b << 1) + (it & 1)) << 7);
    if (lane == 0) {
      unsigned long long tg =
          ((unsigned long long)__float_as_uint(tv) << 32) |
          ((unsigned long long)(unsigned)ti << 7) | (unsigned)it;
      __hip_atomic_store(grp + ((c << 4) | wave), tg,
                         __ATOMIC_RELAXED, __HIP_MEMORY_SCOPE_AGENT);
    }

    // ---- wave0 only: poll all 128 slots (2/lane), reduce, post index ----
    if (wave == 0) {
      unsigned long long t0 = 0, t1 = 0;
      int sp = 0;
      for (;;) {
        t0 = __hip_atomic_load(grp + lane,      __ATOMIC_RELAXED, __HIP_MEMORY_SCOPE_AGENT);
        t1 = __hip_atomic_load(grp + lane + 64, __ATOMIC_RELAXED, __HIP_MEMORY_SCOPE_AGENT);
        bool ok = ((t0 & 127ull) == (unsigned long long)(unsigned)it) &&
                  ((t1 & 127ull) == (unsigned long long)(unsigned)it);
        if (__all(ok)) break;
        if (++sp > SPIN_CAP) break;          // wrong answer >> dead container
        if (sp > 64) __builtin_amdgcn_s_sleep(1);  // tight-poll first
      }
      float v0 = __uint_as_float((unsigned)(t0 >> 32));
      int   i0 = (int)((t0 >> 7) & 0x3FFFF);
      float v1 = __uint_as_float((unsigned)(t1 >> 32));
      int   i1 = (int)((t1 >> 7) & 0x3FFFF);
      bool tk = (v1 > v0) || (v1 == v0 && i1 < i0);
      float cv = tk ? v1 : v0;
      int   ci = tk ? i1 : i0;
      #pragma unroll
      for (int o = 32; o > 0; o >>= 1) {
        float ov = __shfl_xor(cv, o);
        int   oi = __shfl_xor(ci, o);
        bool take = (ov > cv) || (ov == cv && oi < ci);
        cv = take ? ov : cv;
        ci = take ? oi : ci;
      }
      if (lane == 0) {
        sFar = ci;                           // LDS mailbox (index only)
        if (c == 0) out[b * M_ + it] = ci;   // fire-and-forget
      }
    }
    __syncthreads();                         // the ONLY barrier per iteration

    // all waves fetch winner coords themselves: uniform address -> one
    // broadcast request per wave; read-only P, L1/L2-warm, fully parallel.
    const int ci = sFar;
    const float* pw = P + (size_t)ci * 3;
    cx = pw[0]; cy = pw[1]; cz = pw[2];
  }
}

extern "C" void kernel_launch(void* const* d_in, const int* in_sizes, int n_in,
                              void* d_out, int out_size, void* d_ws, size_t ws_size,
                              hipStream_t stream) {
  const float*        pts  = (const float*)d_in[0];
  int*                out  = (int*)d_out;
  unsigned long long* tags = (unsigned long long*)d_ws;

  // zero tag slots each launch (tag 0 never matches it>=1); capture-safe
  hipMemsetAsync(d_ws, 0, (size_t)B_ * 2 * 128 * sizeof(unsigned long long), stream);

  // 144 KiB LDS/block -> 1 block/CU; grid == 256 == CU count -> co-resident.
  fps_kernel<<<dim3(B_ * BPB), dim3(T_), 0, stream>>>(pts, out, tags);
}

// Round 14
// 474.484 us; speedup vs baseline: 1.5310x; 1.5310x over previous
//
#include <hip/hip_runtime.h>
#include <cfloat>

// Farthest Point Sampling: B=32, N=200000, M=128.
// r10 champion topology + (1) 18 pts in VGPR / 8 pts in LDS (DS reads 9->6),
// (2) intra-block reduce via one LDS atomicMax(u64) key per wave,
// (3) bounded-backoff MALL poll (tight 128 tries, then s_sleep; hard cap).
// NOTE r12/r13: identical source died to infra (container unreachable before
// file push, same container both rounds); kernel never executed. Resubmit.
#define B_    32
#define N_    200000
#define M_    128
#define BPB   8                    // blocks per batch
#define T_    1024                 // threads per block
#define PT    26                   // points per thread (13 pairs)
#define NPAIR 13
#define PVP   9                    // pairs in VGPRs (j = 0..17)
#define CHUNK (T_ * PT)            // 26624 points per block; 8*26624 >= N

#define SPIN_CAP (1 << 17)         // hard cap: worst case ~1s total, never a hang

typedef float v2f __attribute__((ext_vector_type(2)));

__global__ __launch_bounds__(T_, 4)
void fps_kernel(const float* __restrict__ pts, int* __restrict__ out,
                unsigned long long* __restrict__ tags) {
#pragma clang fp contract(off)
  const int tid = threadIdx.x;
  const int bid = blockIdx.x;
  // XCD-local batches: blocks round-robin XCDs by bid&7 (measured m09).
  const int xcd = bid & 7;
  const int sl8 = bid >> 3;                  // 0..31 within this XCD
  const int b   = ((sl8 >> 3) << 3) | xcd;   // batch (b&7 == xcd)
  const int c   = sl8 & 7;                   // chunk within batch
  const int wave = tid >> 6;
  const int lane = tid & 63;

  const float* __restrict__ P = pts + (size_t)b * (size_t)(N_ * 3);
  const int base = c * CHUNK + tid;          // this thread's j=0 global index

  // 2 groups x 3 coords x [1024] float4 = 96 KiB -> exactly 1 block/CU
  // (2 blocks would need 192 KiB > 160). Thread-private columns, b128 reads.
  __shared__ float4 sX[2][T_], sY[2][T_], sZ[2][T_];
  __shared__ unsigned long long sKey[2];     // parity-rotated block argmax key
  __shared__ int    sFar;                    // winner index mailbox

  if (tid == 0) { sKey[0] = 0ull; sKey[1] = 0ull; }

  // ---- one-time load ----
  v2f x2[PVP], y2[PVP], z2[PVP], md2[NPAIR];
  #pragma unroll
  for (int p = 0; p < PVP; ++p) {
    const int g0 = base + (2 * p) * T_, g1 = base + (2 * p + 1) * T_;
    float m0, m1;
    if (g0 < N_) {
      const float* q = P + (size_t)g0 * 3;
      x2[p].x = q[0]; y2[p].x = q[1]; z2[p].x = q[2];
      m0 = __builtin_huge_valf();
    } else { x2[p].x = 0.f; y2[p].x = 0.f; z2[p].x = 0.f; m0 = -FLT_MAX; }
    if (g1 < N_) {
      const float* q = P + (size_t)g1 * 3;
      x2[p].y = q[0]; y2[p].y = q[1]; z2[p].y = q[2];
      m1 = __builtin_huge_valf();
    } else { x2[p].y = 0.f; y2[p].y = 0.f; z2[p].y = 0.f; m1 = -FLT_MAX; }
    md2[p].x = m0; md2[p].y = m1;
  }
  #pragma unroll
  for (int g = 0; g < 2; ++g) {
    float qx[4], qy[4], qz[4];
    #pragma unroll
    for (int q = 0; q < 4; ++q) {
      const int j = 18 + 4 * g + q;          // j = 18..25
      const int gg = base + j * T_;
      float m;
      if (gg < N_) {
        const float* pp = P + (size_t)gg * 3;
        qx[q] = pp[0]; qy[q] = pp[1]; qz[q] = pp[2];
        m = __builtin_huge_valf();
      } else { qx[q] = 0.f; qy[q] = 0.f; qz[q] = 0.f; m = -FLT_MAX; }
      const int pr = 9 + 2 * g + (q >> 1);   // pair index 9..12
      if ((q & 1) == 0) md2[pr].x = m; else md2[pr].y = m;
    }
    sX[g][tid] = make_float4(qx[0], qx[1], qx[2], qx[3]);
    sY[g][tid] = make_float4(qy[0], qy[1], qy[2], qy[3]);
    sZ[g][tid] = make_float4(qz[0], qz[1], qz[2], qz[3]);
  }
  asm volatile("" ::: "memory");             // keep LDS staging real (r8 bug)
  __syncthreads();

  float cx = P[0], cy = P[1], cz = P[2];     // initial center = point 0
  if (c == 0 && tid == 0) out[b * M_ + 0] = 0;

  for (int it = 1; it < M_; ++it) {
    // ---- packed distance + running-min + 2-parity-chain argmax ----
    // No exclusion select: chosen point's self-distance is exactly 0
    // (coords bit-exact); min(md,0)=0 never beats any positive min-dist.
    // Packed ops are per-component rn; fp contract(off) forbids pk_fma ->
    // bit-identical to numpy's ((dx*dx + dy*dy) + dz*dz).
    const v2f C_x = {cx, cx}, C_y = {cy, cy}, C_z = {cz, cz};
    float bvE = -FLT_MAX, bvO = -FLT_MAX;    // even-j / odd-j chains
    int   bjE = 0x7FFF,   bjO = 0x7FFF;

    #pragma unroll
    for (int p = 0; p < PVP; ++p) {
      v2f dx = x2[p] - C_x;
      v2f dy = y2[p] - C_y;
      v2f dz = z2[p] - C_z;
      v2f s  = (dx * dx + dy * dy) + dz * dz; // 3 pk_mul + 2 pk_add, no fma
      v2f mm = __builtin_elementwise_min(md2[p], s);  // np.minimum
      md2[p] = mm;
      bool tE = mm.x > bvE;                  // ascending j: strict >
      bvE = tE ? mm.x : bvE;
      bjE = tE ? 2 * p : bjE;
      bool tO = mm.y > bvO;
      bvO = tO ? mm.y : bvO;
      bjO = tO ? 2 * p + 1 : bjO;
    }
    #pragma unroll
    for (int g = 0; g < 2; ++g) {
      float4 qx = sX[g][tid], qy = sY[g][tid], qz = sZ[g][tid];
      #pragma unroll
      for (int h = 0; h < 2; ++h) {          // two pairs per float4 group
        const int p = 9 + 2 * g + h;         // pair index
        v2f X = (h == 0) ? (v2f){qx.x, qx.y} : (v2f){qx.z, qx.w};
        v2f Y = (h == 0) ? (v2f){qy.x, qy.y} : (v2f){qy.z, qy.w};
        v2f Z = (h == 0) ? (v2f){qz.x, qz.y} : (v2f){qz.z, qz.w};
        v2f dx = X - C_x;
        v2f dy = Y - C_y;
        v2f dz = Z - C_z;
        v2f s  = (dx * dx + dy * dy) + dz * dz;
        v2f mm = __builtin_elementwise_min(md2[p], s);
        md2[p] = mm;
        bool tE = mm.x > bvE;
        bvE = tE ? mm.x : bvE;
        bjE = tE ? 2 * p : bjE;
        bool tO = mm.y > bvO;
        bvO = tO ? mm.y : bvO;
        bjO = tO ? 2 * p + 1 : bjO;
      }
    }
    // merge parity chains (tie -> smaller j = smaller global idx)
    bool tk0 = (bvO > bvE) || (bvO == bvE && bjO < bjE);
    float tv = tk0 ? bvO : bvE;
    int   tj = tk0 ? bjO : bjE;
    int   ti = base + tj * T_;               // global idx (< 2^18)

    // ---- wave reduction (64 lanes) ----
    #pragma unroll
    for (int o = 32; o > 0; o >>= 1) {
      float ov = __shfl_xor(tv, o);
      int   oi = __shfl_xor(ti, o);
      bool take = (ov > tv) || (ov == tv && oi < ti);
      tv = take ? ov : tv;
      ti = take ? oi : ti;
    }

    // ---- intra-block reduce: one LDS atomicMax(u64) per wave ----
    // key = (valbits<<32) | (idx ^ 0x3FFFF). tv >= 0 always (j=0 is valid
    // for every thread, md[0] = d >= 0 after first min) -> float bits are
    // unsigned-monotone; inverted 18-bit idx -> ties pick smaller idx.
    if (lane == 0) {
      unsigned long long key =
          ((unsigned long long)__float_as_uint(tv) << 32) |
          (unsigned long long)((unsigned)ti ^ 0x3FFFFu);
      atomicMax(&sKey[it & 1], key);
    }
    if (tid == 0) sKey[(it & 1) ^ 1] = 0ull; // reset other slot pre-barrier:
                                             // its next writers are post-bar
    __syncthreads();                         // barrier #1

    if (wave == 0) {
      unsigned long long* grp = tags + (((b << 1) + (it & 1)) << 3);
      if (lane == 0) {
        // publish block winner: tag = (valbits<<32)|(idx<<7)|iter; one u64
        // word -> RELAXED agent atomics suffice (no buffer_inv).
        unsigned long long k = sKey[it & 1];
        unsigned vbits = (unsigned)(k >> 32);
        unsigned idx   = ((unsigned)k & 0x3FFFFu) ^ 0x3FFFFu;
        unsigned long long tg =
            ((unsigned long long)vbits << 32) |
            ((unsigned long long)idx << 7) | (unsigned)it;
        __hip_atomic_store(grp + c, tg, __ATOMIC_RELAXED, __HIP_MEMORY_SCOPE_AGENT);
      }
      // poll the 8 block tags (lanes 0..7): tight for 128 tries (normal
      // arrival window), then s_sleep backoff; hard cap -> never a hang.
      unsigned long long t = 0;
      if (lane < BPB) {
        int sp = 0;
        for (;;) {
          t = __hip_atomic_load(grp + lane, __ATOMIC_RELAXED, __HIP_MEMORY_SCOPE_AGENT);
          if ((t & 127ull) == (unsigned long long)(unsigned)it) break;
          if (++sp > SPIN_CAP) break;        // wrong answer >> dead container
          if (sp > 128) __builtin_amdgcn_s_sleep(1);
        }
      }
      float cv = (lane < BPB) ? __uint_as_float((unsigned)(t >> 32)) : -FLT_MAX;
      int   ci = (lane < BPB) ? (int)((t >> 7) & 0x3FFFF) : 0x7FFFFFFF;
      #pragma unroll
      for (int o = 4; o > 0; o >>= 1) {
        float ov = __shfl_xor(cv, o);
        int   oi = __shfl_xor(ci, o);
        bool take = (ov > cv) || (ov == cv && oi < ci);
        cv = take ? ov : cv;
        ci = take ? oi : ci;
      }
      if (lane == 0) {
        sFar = ci;                           // index mailbox
        if (c == 0) out[b * M_ + it] = ci;   // fire-and-forget
      }
    }
    __syncthreads();                         // barrier #2

    // all waves fetch winner coords: uniform address -> broadcast load;
    // read-only P (never stale), L1/L2-warm, parallel across waves.
    const int ci = sFar;
    const float* pw = P + (size_t)ci * 3;
    cx = pw[0]; cy = pw[1]; cz = pw[2];
  }
}

extern "C" void kernel_launch(void* const* d_in, const int* in_sizes, int n_in,
                              void* d_out, int out_size, void* d_ws, size_t ws_size,
                              hipStream_t stream) {
  const float*        pts  = (const float*)d_in[0];
  int*                out  = (int*)d_out;
  unsigned long long* tags = (unsigned long long*)d_ws;

  // zero tag slots each launch (tag 0 never matches it>=1); capture-safe
  hipMemsetAsync(d_ws, 0, (size_t)B_ * 2 * BPB * sizeof(unsigned long long), stream);

  // 96 KiB LDS/block -> 1 block/CU; grid == 256 == CU count -> co-resident.
  fps_kernel<<<dim3(B_ * BPB), dim3(T_), 0, stream>>>(pts, out, tags);
}